// Round 1
// baseline (668.192 us; speedup 1.0000x reference)
//
#include <hip/hip_runtime.h>

// Problem constants (fixed by setup_inputs)
#define B_   8
#define C_   64
#define O_   64
#define H_   128
#define W_   128
#define HO_  128
#define WO_  128
#define K2_  9
#define MOFF 18   // 2*K*K offset channels
#define PLANE (H_*W_)   // 16384

// ---------------------------------------------------------------------------
// Kernel 0: one-time transpose of main-conv weights into ws:
//   wT[(c*9+t)*64 + o] = w[(o*64+c)*9 + t]
// so that kernel 2's LDS staging reads are contiguous.
// ---------------------------------------------------------------------------
__global__ __launch_bounds__(256) void wtrans_kernel(const float* __restrict__ w,
                                                     float* __restrict__ wT) {
    int i = blockIdx.x * 256 + threadIdx.x;      // 0 .. 36863
    if (i >= O_ * C_ * K2_) return;
    int o = i & 63;
    int r = i >> 6;
    int t = r % 9;
    int c = r / 9;
    wT[i] = w[(o * C_ + c) * K2_ + t];
}

// ---------------------------------------------------------------------------
// Kernel 1: 3x3 offset conv, 64 -> 18 channels, pad 1, stride 1.
// Block = 128 threads = one output row (b, ho). Thread per wo.
// w_off staged in LDS as lw[c][tap][m] (uniform broadcast reads).
// Output layout [B][18][HO][WO] (same as reference's offset tensor).
// ---------------------------------------------------------------------------
__global__ __launch_bounds__(128) void off_conv_kernel(const float* __restrict__ x,
                                                       const float* __restrict__ w_off,
                                                       const float* __restrict__ b_off,
                                                       float* __restrict__ off_out) {
    __shared__ float lw[C_ * K2_ * MOFF];   // 64*9*18 = 10368 floats = 41.5 KB
    const int tid = threadIdx.x;
    // stage: src flat idx i = m*576 + c*9 + t  -> dst (c*9+t)*18 + m
    for (int i = tid; i < C_ * K2_ * MOFF; i += 128) {
        int m = i / (C_ * K2_);
        int r = i % (C_ * K2_);
        int c = r / K2_;
        int t = r % K2_;
        lw[(c * K2_ + t) * MOFF + m] = w_off[i];
    }
    __syncthreads();

    const int wo = tid;
    const int ho = blockIdx.x;
    const int b  = blockIdx.y;

    float acc[MOFF];
#pragma unroll
    for (int m = 0; m < MOFF; m++) acc[m] = b_off[m];

    const float* xb = x + (size_t)b * C_ * PLANE;
    for (int c = 0; c < C_; c++) {
        const float* plane = xb + c * PLANE;
#pragma unroll
        for (int ki = 0; ki < 3; ki++) {
            int y = ho - 1 + ki;
            if ((unsigned)y >= (unsigned)H_) continue;   // block-uniform branch
#pragma unroll
            for (int kj = 0; kj < 3; kj++) {
                int xx = wo - 1 + kj;
                float v = ((unsigned)xx < (unsigned)W_) ? plane[y * W_ + xx] : 0.f;
                const float* wp = &lw[(c * K2_ + ki * 3 + kj) * MOFF];
#pragma unroll
                for (int m = 0; m < MOFF; m += 2) {
                    float2 w2 = *(const float2*)(wp + m);
                    acc[m]     += v * w2.x;
                    acc[m + 1] += v * w2.y;
                }
            }
        }
    }

    float* op = off_out + ((size_t)b * MOFF) * PLANE + ho * WO_ + wo;
#pragma unroll
    for (int m = 0; m < MOFF; m++) op[m * PLANE] = acc[m];
}

// ---------------------------------------------------------------------------
// Kernel 2: deformable conv. Thread per output pixel, 64 fp32 accumulators.
// Per-tap bilinear corner addresses + masked weights computed ONCE per pixel
// (they do not depend on the input channel), reused across all 64 channels.
// Main-conv weights streamed through LDS in c-chunks of 16: lw[cc][tap][oc].
// Block = 256 threads = 2 output rows.
// ---------------------------------------------------------------------------
#define CCHUNK 16
__global__ __launch_bounds__(256) void dconv_kernel(const float* __restrict__ x,
                                                    const float* __restrict__ off,
                                                    const float* __restrict__ wT,
                                                    const float* __restrict__ bias,
                                                    float* __restrict__ out) {
    __shared__ float lw[CCHUNK * K2_ * O_];   // 16*9*64 floats = 36.9 KB
    const int tid = threadIdx.x;
    const int b  = blockIdx.y;
    const int ho = blockIdx.x * 2 + (tid >> 7);
    const int wo = tid & 127;

    // ---- per-tap bilinear setup (channel-independent) ----
    int   addr[K2_][4];
    float cwt[K2_][4];
    const float* offp = off + (size_t)b * MOFF * PLANE + ho * WO_ + wo;
#pragma unroll
    for (int k = 0; k < K2_; k++) {
        int ki = k / 3, kj = k % 3;
        float dy = offp[(2 * k) * PLANE];
        float dx = offp[(2 * k + 1) * PLANE];
        float py = (float)(ho - 1 + ki) + dy;
        float px = (float)(wo - 1 + kj) + dx;
        float fy = floorf(py), fx = floorf(px);
        float wy = py - fy,    wx = px - fx;
        int y0 = (int)fy, x0 = (int)fx;
        float wgt[4] = { (1.f - wy) * (1.f - wx), (1.f - wy) * wx,
                         wy * (1.f - wx),         wy * wx };
#pragma unroll
        for (int c2 = 0; c2 < 4; c2++) {
            int yy = y0 + (c2 >> 1);
            int xx = x0 + (c2 & 1);
            bool valid = (yy >= 0) && (yy < H_) && (xx >= 0) && (xx < W_);
            int yc = min(max(yy, 0), H_ - 1);
            int xc = min(max(xx, 0), W_ - 1);
            addr[k][c2] = yc * W_ + xc;
            cwt[k][c2]  = valid ? wgt[c2] : 0.f;
        }
    }

    float acc[O_];
#pragma unroll
    for (int o = 0; o < O_; o++) acc[o] = 0.f;

    const float* xb = x + (size_t)b * C_ * PLANE;
    for (int c0 = 0; c0 < C_; c0 += CCHUNK) {
        __syncthreads();
        // stage wT chunk: contiguous range [c0*576, (c0+16)*576)
        const float* src = wT + c0 * (K2_ * O_);
        for (int i = tid; i < CCHUNK * K2_ * O_; i += 256) lw[i] = src[i];
        __syncthreads();

        for (int c = 0; c < CCHUNK; c++) {
            const float* plane = xb + (c0 + c) * PLANE;
            float s[K2_];
#pragma unroll
            for (int k = 0; k < K2_; k++) {
                s[k] = cwt[k][0] * plane[addr[k][0]]
                     + cwt[k][1] * plane[addr[k][1]]
                     + cwt[k][2] * plane[addr[k][2]]
                     + cwt[k][3] * plane[addr[k][3]];
            }
#pragma unroll
            for (int k = 0; k < K2_; k++) {
                const float4* wp = (const float4*)&lw[(c * K2_ + k) * O_];
                float sk = s[k];
#pragma unroll
                for (int o4 = 0; o4 < O_ / 4; o4++) {
                    float4 wv = wp[o4];
                    acc[o4 * 4 + 0] += sk * wv.x;
                    acc[o4 * 4 + 1] += sk * wv.y;
                    acc[o4 * 4 + 2] += sk * wv.z;
                    acc[o4 * 4 + 3] += sk * wv.w;
                }
            }
        }
    }

    float* op = out + ((size_t)b * O_) * PLANE + ho * WO_ + wo;
#pragma unroll
    for (int o = 0; o < O_; o++) op[o * PLANE] = acc[o] + bias[o];
}

// ---------------------------------------------------------------------------
extern "C" void kernel_launch(void* const* d_in, const int* in_sizes, int n_in,
                              void* d_out, int out_size, void* d_ws, size_t ws_size,
                              hipStream_t stream) {
    const float* x     = (const float*)d_in[0];
    const float* w_off = (const float*)d_in[1];
    const float* b_off = (const float*)d_in[2];
    const float* w     = (const float*)d_in[3];
    const float* bias  = (const float*)d_in[4];
    float* out = (float*)d_out;

    float* off_ws = (float*)d_ws;                        // 8*18*128*128 floats = 9.44 MB
    float* wT     = off_ws + (size_t)B_ * MOFF * PLANE;  // 36864 floats = 147 KB

    wtrans_kernel<<<(O_ * C_ * K2_ + 255) / 256, 256, 0, stream>>>(w, wT);
    off_conv_kernel<<<dim3(HO_, B_), 128, 0, stream>>>(x, w_off, b_off, off_ws);
    dconv_kernel<<<dim3(HO_ / 2, B_), 256, 0, stream>>>(x, off_ws, wT, bias, out);
}

// Round 2
// 534.595 us; speedup vs baseline: 1.2499x; 1.2499x over previous
//
#include <hip/hip_runtime.h>

// Problem constants (fixed by setup_inputs)
#define B_   8
#define C_   64
#define O_   64
#define H_   128
#define W_   128
#define HO_  128
#define WO_  128
#define K2_  9
#define MOFF 18          // 2*K*K offset channels
#define PLANE (H_*W_)    // 16384
#define LSTRIDE 152      // LDS row stride in bf16 units (304 B: 16B-aligned, bank stride 12 mod 32)

typedef short bf16x8 __attribute__((ext_vector_type(8)));
typedef float f32x16 __attribute__((ext_vector_type(16)));

__device__ __forceinline__ unsigned short f2bf(float f) {
    // round-to-nearest-even fp32 -> bf16
    unsigned u = __float_as_uint(f);
    u += 0x7fff + ((u >> 16) & 1);
    return (unsigned short)(u >> 16);
}

// ---------------------------------------------------------------------------
// Converters: w [64][64][9] f32 -> wbf [64][576] bf16 (same layout, ck=c*9+t);
// w_off [18][576] f32 -> wobf [32][576] bf16, rows 18..31 zero.
// ---------------------------------------------------------------------------
__global__ __launch_bounds__(256) void cvt_w_kernel(const float* __restrict__ w,
                                                    unsigned short* __restrict__ wbf) {
    int i = blockIdx.x * 256 + threadIdx.x;
    if (i < O_ * C_ * K2_) wbf[i] = f2bf(w[i]);
}

__global__ __launch_bounds__(256) void cvt_woff_kernel(const float* __restrict__ w_off,
                                                       unsigned short* __restrict__ wobf) {
    int i = blockIdx.x * 256 + threadIdx.x;
    if (i < 32 * 576) wobf[i] = (i < MOFF * 576) ? f2bf(w_off[i]) : (unsigned short)0;
}

// ---------------------------------------------------------------------------
// Offset conv via MFMA. Block = 256 thr = 4 waves. Tile: M=32 (18 real out ch)
// x N=128 pixels (one full output row ho of one batch). K=576 in 4 chunks of
// 16 channels (=144 = 9 K-steps of 16). Wave wv covers n in [wv*32, wv*32+32).
// s layout in LDS: ls[pixel][ck_local] bf16, row stride 152.
// ---------------------------------------------------------------------------
__global__ __launch_bounds__(256, 3) void off_mfma_kernel(const float* __restrict__ x,
        const unsigned short* __restrict__ wobf, const float* __restrict__ b_off,
        float* __restrict__ off_out) {
    __shared__ __align__(16) unsigned short ls[128 * LSTRIDE];  // 38,912 B
    __shared__ __align__(16) unsigned short lw[32 * LSTRIDE];   //  9,728 B
    const int tid = threadIdx.x;
    const int p   = tid & 127;          // pixel (= wo, block covers full row)
    const int cg  = tid >> 7;           // 0/1: channel group for sampling
    const int ho  = blockIdx.x & 127;
    const int b   = blockIdx.x >> 7;
    const int lane  = tid & 63;
    const int wv    = tid >> 6;
    const int nbase = wv << 5;
    const int m     = lane & 31;
    const int kh    = lane >> 5;        // K-half within fragment

    const float* xb = x + (size_t)b * C_ * PLANE;
    f32x16 acc = {};

    for (int cc = 0; cc < 4; ++cc) {
        __syncthreads();
        // stage weight chunk: 32 rows x 144 bf16 (18 granules of 16B)
        for (int i = tid; i < 32 * 18; i += 256) {
            int o = i / 18, g = i % 18;
            *(uint4*)&lw[o * LSTRIDE + g * 8] =
                *(const uint4*)&wobf[o * 576 + cc * 144 + g * 8];
        }
        // sampling: this thread fills 8 channels x 9 taps for pixel p
        #pragma unroll 1
        for (int i = 0; i < 8; ++i) {
            int cl = (cg << 3) + i;                 // 0..15
            const float* plane = xb + (cc * 16 + cl) * PLANE;
            unsigned short* dst = &ls[p * LSTRIDE + cl * 9];
            #pragma unroll
            for (int t = 0; t < 9; ++t) {
                int y  = ho - 1 + t / 3;
                int xx = p  - 1 + t % 3;
                float v = ((unsigned)y < (unsigned)H_ && (unsigned)xx < (unsigned)W_)
                          ? plane[y * W_ + xx] : 0.f;
                dst[t] = f2bf(v);
            }
        }
        __syncthreads();
        #pragma unroll
        for (int ks = 0; ks < 9; ++ks) {
            bf16x8 a = *(const bf16x8*)&lw[m * LSTRIDE + ks * 16 + kh * 8];
            bf16x8 s = *(const bf16x8*)&ls[(nbase + m) * LSTRIDE + ks * 16 + kh * 8];
            acc = __builtin_amdgcn_mfma_f32_32x32x16_bf16(a, s, acc, 0, 0, 0);
        }
    }
    // epilogue: D col = pixel (lane&31 + nbase), row = output channel
    const int wo = nbase + m;
    float* op = off_out + (size_t)b * MOFF * PLANE + ho * WO_ + wo;
    #pragma unroll
    for (int r = 0; r < 16; ++r) {
        int mo = (r & 3) + ((r >> 2) << 3) + ((lane >> 5) << 2);
        if (mo < MOFF) op[(size_t)mo * PLANE] = acc[r] + b_off[mo];
    }
}

// ---------------------------------------------------------------------------
// Deformable conv via MFMA. Block = 256 thr = 4 waves. Tile: M=64 out ch x
// N=64 pixels (half-row). Wave wv: m in [(wv&1)*32,+32), n in [(wv>>1)*32,+32).
// Phase 1: bilinear-sample s[(c,k)][pixel] (fp32 gathers, channel-independent
// corner addr/weights precomputed per pixel), store bf16 to LDS.
// Phase 2: 9 K-steps of v_mfma_f32_32x32x16_bf16 per 16-channel chunk.
// ---------------------------------------------------------------------------
__global__ __launch_bounds__(256, 3) void dconv_mfma_kernel(const float* __restrict__ x,
        const float* __restrict__ off, const unsigned short* __restrict__ wbf,
        const float* __restrict__ bias, float* __restrict__ out) {
    __shared__ __align__(16) unsigned short ls[64 * LSTRIDE];   // 19,456 B
    __shared__ __align__(16) unsigned short lw[64 * LSTRIDE];   // 19,456 B
    const int tid = threadIdx.x;
    const int p   = tid & 63;                       // pixel within tile
    const int cg  = tid >> 6;                       // channel group (== wave id)
    const int wo  = ((blockIdx.x & 1) << 6) + p;
    const int ho  = (blockIdx.x >> 1) & 127;
    const int b   = blockIdx.x >> 8;

    // ---- per-pixel bilinear setup (channel-independent) ----
    int   addr[K2_][4];
    float cwt[K2_][4];
    const float* offp = off + (size_t)b * MOFF * PLANE + ho * WO_ + wo;
    #pragma unroll
    for (int k = 0; k < K2_; ++k) {
        int ki = k / 3, kj = k % 3;
        float dy = offp[(2 * k) * PLANE];
        float dx = offp[(2 * k + 1) * PLANE];
        float py = (float)(ho - 1 + ki) + dy;
        float px = (float)(wo - 1 + kj) + dx;
        float fy = floorf(py), fx = floorf(px);
        float wy = py - fy,    wx = px - fx;
        int y0 = (int)fy, x0 = (int)fx;
        float wgt[4] = { (1.f - wy) * (1.f - wx), (1.f - wy) * wx,
                         wy * (1.f - wx),         wy * wx };
        #pragma unroll
        for (int c2 = 0; c2 < 4; ++c2) {
            int yy = y0 + (c2 >> 1);
            int xx = x0 + (c2 & 1);
            bool valid = (yy >= 0) && (yy < H_) && (xx >= 0) && (xx < W_);
            int yc = min(max(yy, 0), H_ - 1);
            int xc = min(max(xx, 0), W_ - 1);
            addr[k][c2] = yc * W_ + xc;
            cwt[k][c2]  = valid ? wgt[c2] : 0.f;
        }
    }

    const int lane  = tid & 63;
    const int wv    = tid >> 6;
    const int mbase = (wv & 1) << 5;
    const int nbase = (wv >> 1) << 5;
    const int m     = lane & 31;
    const int kh    = lane >> 5;
    const float* xb = x + (size_t)b * C_ * PLANE;
    f32x16 acc = {};

    for (int cc = 0; cc < 4; ++cc) {
        __syncthreads();
        // stage weight chunk: 64 rows x 144 bf16 (18 granules of 16B each)
        for (int i = tid; i < 64 * 18; i += 256) {
            int o = i / 18, g = i % 18;
            *(uint4*)&lw[o * LSTRIDE + g * 8] =
                *(const uint4*)&wbf[o * 576 + cc * 144 + g * 8];
        }
        // sampling: this thread fills 4 channels x 9 taps for pixel p
        #pragma unroll 1
        for (int i = 0; i < 4; ++i) {
            int cl = (cg << 2) + i;                 // 0..15
            const float* plane = xb + (cc * 16 + cl) * PLANE;
            unsigned short* dst = &ls[p * LSTRIDE + cl * 9];
            #pragma unroll
            for (int k = 0; k < K2_; ++k) {
                float s = cwt[k][0] * plane[addr[k][0]]
                        + cwt[k][1] * plane[addr[k][1]]
                        + cwt[k][2] * plane[addr[k][2]]
                        + cwt[k][3] * plane[addr[k][3]];
                dst[k] = f2bf(s);
            }
        }
        __syncthreads();
        #pragma unroll
        for (int ks = 0; ks < 9; ++ks) {
            bf16x8 a = *(const bf16x8*)&lw[(mbase + m) * LSTRIDE + ks * 16 + kh * 8];
            bf16x8 s = *(const bf16x8*)&ls[(nbase + m) * LSTRIDE + ks * 16 + kh * 8];
            acc = __builtin_amdgcn_mfma_f32_32x32x16_bf16(a, s, acc, 0, 0, 0);
        }
    }

    // epilogue: D col = pixel, row = output channel
    const int wo_out = ((blockIdx.x & 1) << 6) + nbase + m;
    float* op = out + (size_t)b * O_ * PLANE + ho * WO_ + wo_out;
    #pragma unroll
    for (int r = 0; r < 16; ++r) {
        int mo = mbase + (r & 3) + ((r >> 2) << 3) + ((lane >> 5) << 2);
        op[(size_t)mo * PLANE] = acc[r] + bias[mo];
    }
}

// ---------------------------------------------------------------------------
extern "C" void kernel_launch(void* const* d_in, const int* in_sizes, int n_in,
                              void* d_out, int out_size, void* d_ws, size_t ws_size,
                              hipStream_t stream) {
    const float* x     = (const float*)d_in[0];
    const float* w_off = (const float*)d_in[1];
    const float* b_off = (const float*)d_in[2];
    const float* w     = (const float*)d_in[3];
    const float* bias  = (const float*)d_in[4];
    float* out = (float*)d_out;

    float* off_ws = (float*)d_ws;                                   // 8*18*16384 f32 = 9.44 MB
    unsigned short* wbf  = (unsigned short*)(off_ws + (size_t)B_ * MOFF * PLANE); // 36864 bf16
    unsigned short* wobf = wbf + O_ * C_ * K2_;                     // 32*576 bf16

    cvt_w_kernel  <<<(O_ * C_ * K2_ + 255) / 256, 256, 0, stream>>>(w, wbf);
    cvt_woff_kernel<<<(32 * 576 + 255) / 256,     256, 0, stream>>>(w_off, wobf);
    off_mfma_kernel<<<B_ * HO_,      256, 0, stream>>>(x, wobf, b_off, off_ws);
    dconv_mfma_kernel<<<B_ * HO_ * 2, 256, 0, stream>>>(x, off_ws, wbf, bias, out);
}

// Round 4
// 377.375 us; speedup vs baseline: 1.7706x; 1.4166x over previous
//
#include <hip/hip_runtime.h>

// Problem constants (fixed by setup_inputs)
#define B_   8
#define C_   64
#define O_   64
#define H_   128
#define W_   128
#define HO_  128
#define WO_  128
#define K2_  9
#define MOFF 18          // 2*K*K offset channels
#define PLANE (H_*W_)    // 16384
#define KTOT 576         // C_*K2_
// LDS row stride in bf16 units: 304 B = 19 x 16B. Bank-group stride 12 mod 32
// (odd multiple of 4) -> b128 reads/writes across consecutive rows are
// conflict-free.
#define LSTRIDE 152

typedef short bf16x8 __attribute__((ext_vector_type(8)));
typedef float f32x16 __attribute__((ext_vector_type(16)));

__device__ __forceinline__ unsigned short f2bf(float f) {
    // round-to-nearest-even fp32 -> bf16
    unsigned u = __float_as_uint(f);
    u += 0x7fff + ((u >> 16) & 1);
    return (unsigned short)(u >> 16);
}

// ---------------------------------------------------------------------------
// cvt_w: main-conv weights -> bf16 rows [o][576] in TAP-MAJOR chunk order:
//   pos = cc*144 + t*16 + cl   <->   w[o][c = cc*16+cl][tap t]
// (dconv's sampler writes samples at the same pos bijection, so the MFMA
// contraction pairs correctly; fragment math is purely positional.)
// ---------------------------------------------------------------------------
__global__ __launch_bounds__(256) void cvt_w_kernel(const float* __restrict__ w,
                                                    unsigned short* __restrict__ wbf) {
    int i = blockIdx.x * 256 + threadIdx.x;     // 64*576 = 36864
    if (i >= O_ * KTOT) return;
    int o = i / KTOT, pos = i % KTOT;
    int cc = pos / 144, r = pos % 144, t = r / 16, cl = r % 16;
    wbf[i] = f2bf(w[o * KTOT + (cc * 16 + cl) * 9 + t]);
}

// cvt_woff: R2-verbatim. Row-major [o][k], k = c*9+t; rows 18..31 zero.
__global__ __launch_bounds__(256) void cvt_woff_kernel(const float* __restrict__ w_off,
                                                       unsigned short* __restrict__ wobf) {
    int i = blockIdx.x * 256 + threadIdx.x;     // 32*576 = 18432
    if (i < 32 * KTOT) wobf[i] = (i < MOFF * KTOT) ? f2bf(w_off[i]) : (unsigned short)0;
}

// ---------------------------------------------------------------------------
// Offset conv via MFMA — R2-verbatim except the XCD band swizzle.
// Block = (b,ho): M=32 (18 used) x N=128 pixels. k-order c*9+t on both sides.
// ---------------------------------------------------------------------------
__global__ __launch_bounds__(256, 2) void off_mfma_kernel(const float* __restrict__ x,
        const unsigned short* __restrict__ wobf, const float* __restrict__ b_off,
        float* __restrict__ off_out) {
    __shared__ __align__(16) unsigned short ls[128 * LSTRIDE];  // 38,912 B
    __shared__ __align__(16) unsigned short lw[32 * LSTRIDE];   //  9,728 B
    const int tid = threadIdx.x;
    const int id  = blockIdx.x;                 // 1024
    const int ho  = (id & 7) * 16 + ((id >> 3) & 15);   // XCD band swizzle
    const int b   = id >> 7;
    const int p   = tid & 127;          // pixel (= wo, block covers full row)
    const int cg  = tid >> 7;           // 0/1: channel group for sampling
    const int lane  = tid & 63;
    const int wv    = tid >> 6;
    const int nbase = wv << 5;
    const int m     = lane & 31;
    const int kh    = lane >> 5;        // K-half within fragment

    const float* xb = x + (size_t)b * C_ * PLANE;
    f32x16 acc = {};

    for (int cc = 0; cc < 4; ++cc) {
        __syncthreads();
        // stage weight chunk: 32 rows x 144 bf16 (18 granules of 16B)
        for (int i = tid; i < 32 * 18; i += 256) {
            int o = i / 18, g = i % 18;
            *(uint4*)&lw[o * LSTRIDE + g * 8] =
                *(const uint4*)&wobf[o * KTOT + cc * 144 + g * 8];
        }
        // sampling: this thread fills 8 channels x 9 taps for pixel p
        #pragma unroll 1
        for (int i = 0; i < 8; ++i) {
            int cl = (cg << 3) + i;                 // 0..15
            const float* plane = xb + (cc * 16 + cl) * PLANE;
            unsigned short* dst = &ls[p * LSTRIDE + cl * 9];
            #pragma unroll
            for (int t = 0; t < 9; ++t) {
                int y  = ho - 1 + t / 3;
                int xx = p  - 1 + t % 3;
                float v = ((unsigned)y < (unsigned)H_ && (unsigned)xx < (unsigned)W_)
                          ? plane[y * W_ + xx] : 0.f;
                dst[t] = f2bf(v);
            }
        }
        __syncthreads();
        #pragma unroll
        for (int ks = 0; ks < 9; ++ks) {
            bf16x8 a = *(const bf16x8*)&lw[m * LSTRIDE + ks * 16 + kh * 8];
            bf16x8 s = *(const bf16x8*)&ls[(nbase + m) * LSTRIDE + ks * 16 + kh * 8];
            acc = __builtin_amdgcn_mfma_f32_32x32x16_bf16(a, s, acc, 0, 0, 0);
        }
    }
    // epilogue: D col = pixel (lane&31 + nbase), row = output channel
    const int wo = nbase + m;
    float* op = off_out + (size_t)b * MOFF * PLANE + ho * WO_ + wo;
    #pragma unroll
    for (int r = 0; r < 16; ++r) {
        int mo = (r & 3) + ((r >> 2) << 3) + (kh << 2);
        if (mo < MOFF) op[(size_t)mo * PLANE] = acc[r] + b_off[mo];
    }
}

// ---------------------------------------------------------------------------
// Deformable conv via MFMA. Block = (b,ho): M=64 out-ch x N=128 pixels.
// 4 waves as 2x2: mbase=(wv&1)*32, nb0=(wv>>1)*64 (2 B-fragments, 2 accs).
// Sampling is per-(pixel, tap): thread gh=0 does taps 0..4, gh=1 taps 4..8
// (tap 4 duplicated with bit-identical values -> benign same-address write).
// Corner addrs/weights computed once per tap, reused across 16 channels;
// samples written tap-major (pos = t*16 + cl) as two aligned ds_write_b128.
// ---------------------------------------------------------------------------
__global__ __launch_bounds__(256, 2) void dconv_mfma_kernel(const float* __restrict__ x,
        const float* __restrict__ off, const unsigned short* __restrict__ wbf,
        const float* __restrict__ bias, float* __restrict__ out) {
    __shared__ __align__(16) unsigned short ls[128 * LSTRIDE];  // 38,912 B
    __shared__ __align__(16) unsigned short lw[64 * LSTRIDE];   // 19,456 B
    const int tid = threadIdx.x;
    const int id  = blockIdx.x;                 // 1024
    const int ho  = (id & 7) * 16 + ((id >> 3) & 15);   // XCD band swizzle
    const int b   = id >> 7;
    const int p   = tid & 127;                  // pixel = wo
    const int gh  = tid >> 7;                   // tap-group: 0 -> 0..4, 1 -> 4..8
    const int lane = tid & 63;
    const int wv   = tid >> 6;
    const int mbase = (wv & 1) << 5;
    const int nb0   = (wv >> 1) << 6;           // 0 or 64
    const int m  = lane & 31;
    const int kh = lane >> 5;
    const int t0 = gh << 2;                     // 0 or 4

    // ---- per-(pixel, tap-subset) bilinear setup (channel-independent) ----
    int   addr[5][4];
    float cwt[5][4];
    const float* offp = off + (size_t)b * MOFF * PLANE + ho * WO_ + p;
    #pragma unroll
    for (int i = 0; i < 5; ++i) {
        int t = t0 + i;
        float dy = offp[(2 * t) * PLANE];
        float dx = offp[(2 * t + 1) * PLANE];
        float py = (float)(ho - 1 + t / 3) + dy;
        float px = (float)(p  - 1 + t % 3) + dx;
        float fy = floorf(py), fx = floorf(px);
        float wy = py - fy,    wx = px - fx;
        int y0 = (int)fy, x0 = (int)fx;
        float wgt[4] = { (1.f - wy) * (1.f - wx), (1.f - wy) * wx,
                         wy * (1.f - wx),         wy * wx };
        #pragma unroll
        for (int c2 = 0; c2 < 4; ++c2) {
            int yy = y0 + (c2 >> 1);
            int xx = x0 + (c2 & 1);
            bool valid = ((unsigned)yy < (unsigned)H_) && ((unsigned)xx < (unsigned)W_);
            int yc = min(max(yy, 0), H_ - 1);
            int xc = min(max(xx, 0), W_ - 1);
            addr[i][c2] = yc * W_ + xc;
            cwt[i][c2]  = valid ? wgt[c2] : 0.f;
        }
    }

    const float* xb = x + (size_t)b * C_ * PLANE;
    f32x16 acc[2] = {};
    for (int cc = 0; cc < 4; ++cc) {
        __syncthreads();                        // prev MFMA done with ls/lw
        // stage weight chunk: 64 rows x 144 bf16 (18 granules of 16B)
        for (int i = tid; i < 64 * 18; i += 256) {
            int o = i / 18, g = i % 18;
            *(uint4*)&lw[o * LSTRIDE + g * 8] =
                *(const uint4*)&wbf[o * KTOT + cc * 144 + g * 8];
        }
        // sampling: 5 taps x 16 channels, two b128 writes per tap
        const float* xcc = xb + cc * 16 * PLANE;
        #pragma unroll
        for (int i = 0; i < 5; ++i) {
            const float* p0 = xcc + addr[i][0];
            const float* p1 = xcc + addr[i][1];
            const float* p2 = xcc + addr[i][2];
            const float* p3 = xcc + addr[i][3];
            float w0 = cwt[i][0], w1 = cwt[i][1], w2 = cwt[i][2], w3 = cwt[i][3];
            bf16x8 v0, v1;
            #pragma unroll
            for (int cl = 0; cl < 8; ++cl) {
                float s = w0 * p0[cl * PLANE] + w1 * p1[cl * PLANE]
                        + w2 * p2[cl * PLANE] + w3 * p3[cl * PLANE];
                v0[cl] = (short)f2bf(s);
            }
            #pragma unroll
            for (int cl = 0; cl < 8; ++cl) {
                float s = w0 * p0[(8 + cl) * PLANE] + w1 * p1[(8 + cl) * PLANE]
                        + w2 * p2[(8 + cl) * PLANE] + w3 * p3[(8 + cl) * PLANE];
                v1[cl] = (short)f2bf(s);
            }
            int t = t0 + i;
            *(bf16x8*)&ls[p * LSTRIDE + t * 16]     = v0;
            *(bf16x8*)&ls[p * LSTRIDE + t * 16 + 8] = v1;
        }
        __syncthreads();                        // ls + lw ready
        #pragma unroll
        for (int ks = 0; ks < 9; ++ks) {
            bf16x8 a  = *(const bf16x8*)&lw[(mbase + m) * LSTRIDE + ks * 16 + kh * 8];
            bf16x8 s0 = *(const bf16x8*)&ls[(nb0 + m) * LSTRIDE + ks * 16 + kh * 8];
            bf16x8 s1 = *(const bf16x8*)&ls[(nb0 + 32 + m) * LSTRIDE + ks * 16 + kh * 8];
            acc[0] = __builtin_amdgcn_mfma_f32_32x32x16_bf16(a, s0, acc[0], 0, 0, 0);
            acc[1] = __builtin_amdgcn_mfma_f32_32x32x16_bf16(a, s1, acc[1], 0, 0, 0);
        }
    }

    // epilogue: D col = pixel, row = out channel (32x32 C/D layout)
    #pragma unroll
    for (int nt = 0; nt < 2; ++nt) {
        int col = nb0 + nt * 32 + m;
        float* op = out + (size_t)b * O_ * PLANE + ho * WO_ + col;
        #pragma unroll
        for (int r = 0; r < 16; ++r) {
            int mo = mbase + (r & 3) + ((r >> 2) << 3) + (kh << 2);
            op[(size_t)mo * PLANE] = acc[nt][r] + bias[mo];
        }
    }
}

// ---------------------------------------------------------------------------
extern "C" void kernel_launch(void* const* d_in, const int* in_sizes, int n_in,
                              void* d_out, int out_size, void* d_ws, size_t ws_size,
                              hipStream_t stream) {
    const float* x     = (const float*)d_in[0];
    const float* w_off = (const float*)d_in[1];
    const float* b_off = (const float*)d_in[2];
    const float* w     = (const float*)d_in[3];
    const float* bias  = (const float*)d_in[4];
    float* out = (float*)d_out;

    float* off_ws = (float*)d_ws;                                   // 9.44 MB
    unsigned short* wbf  = (unsigned short*)(off_ws + (size_t)B_ * MOFF * PLANE); // 36864 bf16 (tap-major)
    unsigned short* wobf = wbf + O_ * KTOT;                         // 18432 bf16 (R2 order)

    cvt_w_kernel   <<<(O_ * KTOT + 255) / 256, 256, 0, stream>>>(w, wbf);
    cvt_woff_kernel<<<(32 * KTOT + 255) / 256, 256, 0, stream>>>(w_off, wobf);
    off_mfma_kernel  <<<B_ * HO_, 256, 0, stream>>>(x, wobf, b_off, off_ws);
    dconv_mfma_kernel<<<B_ * HO_, 256, 0, stream>>>(x, off_ws, wbf, bias, out);
}

// Round 5
// 361.120 us; speedup vs baseline: 1.8503x; 1.0450x over previous
//
#include <hip/hip_runtime.h>

// Problem constants (fixed by setup_inputs)
#define B_   8
#define C_   64
#define O_   64
#define H_   128
#define W_   128
#define HO_  128
#define WO_  128
#define K2_  9
#define MOFF 18          // 2*K*K offset channels
#define PLANE (H_*W_)    // 16384
#define KTOT 576         // C_*K2_
// LDS row stride in bf16 units: 304 B = 19 x 16B groups. Group stride 19 mod 32
// (odd) -> b128 ops across consecutive rows are conflict-free.
#define LSTRIDE 152

typedef short bf16x8 __attribute__((ext_vector_type(8)));
typedef float f32x16 __attribute__((ext_vector_type(16)));

__device__ __forceinline__ unsigned short f2bf(float f) {
    // round-to-nearest-even fp32 -> bf16
    unsigned u = __float_as_uint(f);
    u += 0x7fff + ((u >> 16) & 1);
    return (unsigned short)(u >> 16);
}

// ---------------------------------------------------------------------------
// cvt_w: main-conv weights -> bf16 rows [o][576] in TAP-MAJOR chunk order:
//   pos = cc*144 + t*16 + cl   <->   w[o][c = cc*16+cl][tap t]
// Sampler writes ls at the same pos bijection -> contraction pairs correctly.
// ---------------------------------------------------------------------------
__global__ __launch_bounds__(256) void cvt_w_kernel(const float* __restrict__ w,
                                                    unsigned short* __restrict__ wbf) {
    int i = blockIdx.x * 256 + threadIdx.x;     // 64*576 = 36864
    if (i >= O_ * KTOT) return;
    int o = i / KTOT, pos = i % KTOT;
    int cc = pos / 144, r = pos % 144, t = r / 16, cl = r % 16;
    wbf[i] = f2bf(w[o * KTOT + (cc * 16 + cl) * 9 + t]);
}

// cvt_woff: offset-conv weights, same TAP-MAJOR order, 32 rows (o>=18 zero).
__global__ __launch_bounds__(256) void cvt_woff_kernel(const float* __restrict__ w_off,
                                                       unsigned short* __restrict__ wobf) {
    int i = blockIdx.x * 256 + threadIdx.x;     // 32*576 = 18432
    if (i >= 32 * KTOT) return;
    int o = i / KTOT, pos = i % KTOT;
    int cc = pos / 144, r = pos % 144, t = r / 16, cl = r % 16;
    wobf[i] = (o < MOFF) ? f2bf(w_off[o * KTOT + (cc * 16 + cl) * 9 + t])
                         : (unsigned short)0;
}

// ---------------------------------------------------------------------------
// Offset conv via MFMA. Block = (b,ho): M=32 (18 used) x N=128 pixels.
// Tap-major ls; weights read global->VGPR per chunk (no lw LDS).
// Sampling per (pixel, tap-group): gh=0 taps 0..4, gh=1 taps 4..8 (tap 4
// duplicated, bit-identical). 16 channel loads + two b128 writes per tap.
// ---------------------------------------------------------------------------
__global__ __launch_bounds__(256, 4) void off_mfma_kernel(const float* __restrict__ x,
        const unsigned short* __restrict__ wobf, const float* __restrict__ b_off,
        float* __restrict__ off_out) {
    __shared__ __align__(16) unsigned short ls[128 * LSTRIDE];  // 38,912 B
    const int tid = threadIdx.x;
    const int id  = blockIdx.x;                 // 1024
    const int ho  = (id & 7) * 16 + ((id >> 3) & 15);   // XCD band swizzle
    const int b   = id >> 7;
    const int p   = tid & 127;                  // pixel = wo
    const int gh  = tid >> 7;                   // tap group
    const int t0  = gh << 2;                    // 0 or 4
    const int lane  = tid & 63;
    const int wv    = tid >> 6;
    const int nbase = wv << 5;
    const int m     = lane & 31;
    const int kh    = lane >> 5;

    const float* xb = x + (size_t)b * C_ * PLANE;
    f32x16 acc = {};

    for (int cc = 0; cc < 4; ++cc) {
        __syncthreads();                        // prev MFMA done with ls
        // A-fragments: direct global->reg (L2-hot), latency hidden by sampling
        bf16x8 af[9];
        #pragma unroll
        for (int ks = 0; ks < 9; ++ks)
            af[ks] = *(const bf16x8*)&wobf[m * KTOT + cc * 144 + ks * 16 + kh * 8];
        // sampling: 5 taps x 16 channels (regular grid, zero-pad OOB)
        const float* xcc = xb + cc * 16 * PLANE;
        #pragma unroll
        for (int i = 0; i < 5; ++i) {
            const int t = t0 + i;
            const int y  = ho - 1 + t / 3;
            const int xx = p  - 1 + t % 3;
            const bool ok = ((unsigned)y < (unsigned)H_) && ((unsigned)xx < (unsigned)W_);
            const float* rp = xcc + y * W_ + xx;
            bf16x8 v0, v1;
            #pragma unroll
            for (int cl = 0; cl < 8; ++cl)
                v0[cl] = (short)f2bf(ok ? rp[cl * PLANE] : 0.f);
            #pragma unroll
            for (int cl = 0; cl < 8; ++cl)
                v1[cl] = (short)f2bf(ok ? rp[(8 + cl) * PLANE] : 0.f);
            *(bf16x8*)&ls[p * LSTRIDE + t * 16]     = v0;
            *(bf16x8*)&ls[p * LSTRIDE + t * 16 + 8] = v1;
        }
        __syncthreads();                        // ls ready (vmcnt drained)
        #pragma unroll
        for (int ks = 0; ks < 9; ++ks) {
            bf16x8 s = *(const bf16x8*)&ls[(nbase + m) * LSTRIDE + ks * 16 + kh * 8];
            acc = __builtin_amdgcn_mfma_f32_32x32x16_bf16(af[ks], s, acc, 0, 0, 0);
        }
    }
    // epilogue: D col = pixel (nbase+m), row = output channel
    float* op = off_out + (size_t)b * MOFF * PLANE + ho * WO_ + (nbase + m);
    #pragma unroll
    for (int r = 0; r < 16; ++r) {
        int mo = (r & 3) + ((r >> 2) << 3) + (kh << 2);
        if (mo < MOFF) op[(size_t)mo * PLANE] = acc[r] + b_off[mo];
    }
}

// ---------------------------------------------------------------------------
// Deformable conv via MFMA. Block = (b,ho): M=64 out-ch x N=128 pixels.
// 4 waves as 2x2: mbase=(wv&1)*32, nb0=(wv>>1)*64 (2 B-fragments, 2 accs).
// Sampling per (pixel, tap-group) with bilinear corners; tap-major b128 writes.
// Weights read global->VGPR per chunk (no lw LDS) -> 38.9 KB LDS, 4 blocks/CU.
// ---------------------------------------------------------------------------
__global__ __launch_bounds__(256, 4) void dconv_mfma_kernel(const float* __restrict__ x,
        const float* __restrict__ off, const unsigned short* __restrict__ wbf,
        const float* __restrict__ bias, float* __restrict__ out) {
    __shared__ __align__(16) unsigned short ls[128 * LSTRIDE];  // 38,912 B
    const int tid = threadIdx.x;
    const int id  = blockIdx.x;                 // 1024
    const int ho  = (id & 7) * 16 + ((id >> 3) & 15);   // XCD band swizzle
    const int b   = id >> 7;
    const int p   = tid & 127;                  // pixel = wo
    const int gh  = tid >> 7;                   // tap-group: 0 -> 0..4, 1 -> 4..8
    const int lane = tid & 63;
    const int wv   = tid >> 6;
    const int mbase = (wv & 1) << 5;
    const int nb0   = (wv >> 1) << 6;           // 0 or 64
    const int m  = lane & 31;
    const int kh = lane >> 5;
    const int t0 = gh << 2;                     // 0 or 4

    // ---- per-(pixel, tap-subset) bilinear setup (channel-independent) ----
    int   addr[5][4];
    float cwt[5][4];
    const float* offp = off + (size_t)b * MOFF * PLANE + ho * WO_ + p;
    #pragma unroll
    for (int i = 0; i < 5; ++i) {
        int t = t0 + i;
        float dy = offp[(2 * t) * PLANE];
        float dx = offp[(2 * t + 1) * PLANE];
        float py = (float)(ho - 1 + t / 3) + dy;
        float px = (float)(p  - 1 + t % 3) + dx;
        float fy = floorf(py), fx = floorf(px);
        float wy = py - fy,    wx = px - fx;
        int y0 = (int)fy, x0 = (int)fx;
        float wgt[4] = { (1.f - wy) * (1.f - wx), (1.f - wy) * wx,
                         wy * (1.f - wx),         wy * wx };
        #pragma unroll
        for (int c2 = 0; c2 < 4; ++c2) {
            int yy = y0 + (c2 >> 1);
            int xx = x0 + (c2 & 1);
            bool valid = ((unsigned)yy < (unsigned)H_) && ((unsigned)xx < (unsigned)W_);
            int yc = min(max(yy, 0), H_ - 1);
            int xc = min(max(xx, 0), W_ - 1);
            addr[i][c2] = yc * W_ + xc;
            cwt[i][c2]  = valid ? wgt[c2] : 0.f;
        }
    }

    const float* xb = x + (size_t)b * C_ * PLANE;
    f32x16 acc[2] = {};
    for (int cc = 0; cc < 4; ++cc) {
        __syncthreads();                        // prev MFMA done with ls
        // A-fragments: direct global->reg (L2-hot), latency hidden by sampling
        bf16x8 af[9];
        #pragma unroll
        for (int ks = 0; ks < 9; ++ks)
            af[ks] = *(const bf16x8*)&wbf[(mbase + m) * KTOT + cc * 144 + ks * 16 + kh * 8];
        // sampling: 5 taps x 16 channels, two b128 writes per tap
        const float* xcc = xb + cc * 16 * PLANE;
        #pragma unroll
        for (int i = 0; i < 5; ++i) {
            const float* p0 = xcc + addr[i][0];
            const float* p1 = xcc + addr[i][1];
            const float* p2 = xcc + addr[i][2];
            const float* p3 = xcc + addr[i][3];
            float w0 = cwt[i][0], w1 = cwt[i][1], w2 = cwt[i][2], w3 = cwt[i][3];
            bf16x8 v0, v1;
            #pragma unroll
            for (int cl = 0; cl < 8; ++cl) {
                float s = w0 * p0[cl * PLANE] + w1 * p1[cl * PLANE]
                        + w2 * p2[cl * PLANE] + w3 * p3[cl * PLANE];
                v0[cl] = (short)f2bf(s);
            }
            #pragma unroll
            for (int cl = 0; cl < 8; ++cl) {
                float s = w0 * p0[(8 + cl) * PLANE] + w1 * p1[(8 + cl) * PLANE]
                        + w2 * p2[(8 + cl) * PLANE] + w3 * p3[(8 + cl) * PLANE];
                v1[cl] = (short)f2bf(s);
            }
            int t = t0 + i;
            *(bf16x8*)&ls[p * LSTRIDE + t * 16]     = v0;
            *(bf16x8*)&ls[p * LSTRIDE + t * 16 + 8] = v1;
        }
        __syncthreads();                        // ls ready (vmcnt drained)
        #pragma unroll
        for (int ks = 0; ks < 9; ++ks) {
            bf16x8 s0 = *(const bf16x8*)&ls[(nb0 + m) * LSTRIDE + ks * 16 + kh * 8];
            bf16x8 s1 = *(const bf16x8*)&ls[(nb0 + 32 + m) * LSTRIDE + ks * 16 + kh * 8];
            acc[0] = __builtin_amdgcn_mfma_f32_32x32x16_bf16(af[ks], s0, acc[0], 0, 0, 0);
            acc[1] = __builtin_amdgcn_mfma_f32_32x32x16_bf16(af[ks], s1, acc[1], 0, 0, 0);
        }
    }

    // epilogue: D col = pixel, row = out channel (32x32 C/D layout)
    #pragma unroll
    for (int nt = 0; nt < 2; ++nt) {
        int col = nb0 + nt * 32 + m;
        float* op = out + (size_t)b * O_ * PLANE + ho * WO_ + col;
        #pragma unroll
        for (int r = 0; r < 16; ++r) {
            int mo = mbase + (r & 3) + ((r >> 2) << 3) + (kh << 2);
            op[(size_t)mo * PLANE] = acc[nt][r] + bias[mo];
        }
    }
}

// ---------------------------------------------------------------------------
extern "C" void kernel_launch(void* const* d_in, const int* in_sizes, int n_in,
                              void* d_out, int out_size, void* d_ws, size_t ws_size,
                              hipStream_t stream) {
    const float* x     = (const float*)d_in[0];
    const float* w_off = (const float*)d_in[1];
    const float* b_off = (const float*)d_in[2];
    const float* w     = (const float*)d_in[3];
    const float* bias  = (const float*)d_in[4];
    float* out = (float*)d_out;

    float* off_ws = (float*)d_ws;                                   // 9.44 MB
    unsigned short* wbf  = (unsigned short*)(off_ws + (size_t)B_ * MOFF * PLANE); // 36864 bf16 (tap-major)
    unsigned short* wobf = wbf + O_ * KTOT;                         // 18432 bf16 (tap-major)

    cvt_w_kernel   <<<(O_ * KTOT + 255) / 256, 256, 0, stream>>>(w, wbf);
    cvt_woff_kernel<<<(32 * KTOT + 255) / 256, 256, 0, stream>>>(w_off, wobf);
    off_mfma_kernel  <<<B_ * HO_, 256, 0, stream>>>(x, wobf, b_off, off_ws);
    dconv_mfma_kernel<<<B_ * HO_, 256, 0, stream>>>(x, off_ws, wbf, bias, out);
}

// Round 6
// 290.237 us; speedup vs baseline: 2.3022x; 1.2442x over previous
//
#include <hip/hip_runtime.h>

// Problem constants (fixed by setup_inputs)
#define B_   8
#define C_   64
#define O_   64
#define H_   128
#define W_   128
#define HO_  128
#define WO_  128
#define K2_  9
#define MOFF 18          // 2*K*K offset channels
#define PLANE (H_*W_)    // 16384
#define KTOT 576         // C_*K2_
// LDS row stride in bf16 units: 304 B = 19 x 16B groups. Group stride 19 mod 32
// (odd) -> b128 ops across consecutive rows are conflict-free.
#define LSTRIDE 152

typedef short bf16x8 __attribute__((ext_vector_type(8)));
typedef float f32x16 __attribute__((ext_vector_type(16)));

__device__ __forceinline__ unsigned short f2bf(float f) {
    // round-to-nearest-even fp32 -> bf16
    unsigned u = __float_as_uint(f);
    u += 0x7fff + ((u >> 16) & 1);
    return (unsigned short)(u >> 16);
}
__device__ __forceinline__ float bf2f(short v) {
    return __uint_as_float(((unsigned)(unsigned short)v) << 16);
}

// ---------------------------------------------------------------------------
// cvt_w: main-conv weights -> bf16 rows [o][576] in TAP-MAJOR chunk order:
//   pos = cc*144 + t*16 + cl   <->   w[o][c = cc*16+cl][tap t]
// ---------------------------------------------------------------------------
__global__ __launch_bounds__(256) void cvt_w_kernel(const float* __restrict__ w,
                                                    unsigned short* __restrict__ wbf) {
    int i = blockIdx.x * 256 + threadIdx.x;     // 64*576 = 36864
    if (i >= O_ * KTOT) return;
    int o = i / KTOT, pos = i % KTOT;
    int cc = pos / 144, r = pos % 144, t = r / 16, cl = r % 16;
    wbf[i] = f2bf(w[o * KTOT + (cc * 16 + cl) * 9 + t]);
}

// cvt_woff: offset-conv weights, same TAP-MAJOR order, 32 rows (o>=18 zero).
__global__ __launch_bounds__(256) void cvt_woff_kernel(const float* __restrict__ w_off,
                                                       unsigned short* __restrict__ wobf) {
    int i = blockIdx.x * 256 + threadIdx.x;     // 32*576 = 18432
    if (i >= 32 * KTOT) return;
    int o = i / KTOT, pos = i % KTOT;
    int cc = pos / 144, r = pos % 144, t = r / 16, cl = r % 16;
    wobf[i] = (o < MOFF) ? f2bf(w_off[o * KTOT + (cc * 16 + cl) * 9 + t])
                         : (unsigned short)0;
}

// ---------------------------------------------------------------------------
// NHWC bf16 transpose: xt[((b*H+y)*W+px)*64 + c] = bf16(x[((b*64+c)*H+y)*W+px])
// Block = (b,y): read 64ch x 128px coalesced, LDS transpose, write coalesced.
// ---------------------------------------------------------------------------
__global__ __launch_bounds__(256) void nhwc_kernel(const float* __restrict__ x,
                                                   unsigned short* __restrict__ xt) {
    __shared__ unsigned short T[64 * 130];      // stride 130 (odd 16B groups)
    const int tid = threadIdx.x;
    const int y = blockIdx.x & 127;
    const int b = blockIdx.x >> 7;
    const float* src = x + (size_t)b * C_ * PLANE + y * W_;
    for (int i = tid; i < 64 * 128; i += 256) {
        int c = i >> 7, px = i & 127;
        T[c * 130 + px] = f2bf(src[c * PLANE + px]);
    }
    __syncthreads();
    unsigned short* dst = xt + ((size_t)b * PLANE + y * W_) * 64;
    for (int j = tid; j < 128 * 16; j += 256) {
        int px = j >> 4, c4 = (j & 15) * 4;
        ushort4 v = { (unsigned short)T[(c4 + 0) * 130 + px],
                      (unsigned short)T[(c4 + 1) * 130 + px],
                      (unsigned short)T[(c4 + 2) * 130 + px],
                      (unsigned short)T[(c4 + 3) * 130 + px] };
        *(ushort4*)&dst[px * 64 + c4] = v;
    }
}

// ---------------------------------------------------------------------------
// Offset conv via MFMA. Block = (b,ho): M=32 (18 used) x N=128 pixels.
// NHWC bf16 input: one tap = two b128 loads (16 channels contiguous), no cvt.
// Weights global->VGPR per chunk. Tap-major ls (pos = t*16+cl).
// ---------------------------------------------------------------------------
__global__ __launch_bounds__(256, 4) void off_mfma_kernel(const unsigned short* __restrict__ xt,
        const unsigned short* __restrict__ wobf, const float* __restrict__ b_off,
        float* __restrict__ off_out) {
    __shared__ __align__(16) unsigned short ls[128 * LSTRIDE];  // 38,912 B
    const int tid = threadIdx.x;
    const int id  = blockIdx.x;                 // 1024
    const int ho  = (id & 7) * 16 + ((id >> 3) & 15);   // XCD band swizzle
    const int b   = id >> 7;
    const int p   = tid & 127;                  // pixel = wo
    const int gh  = tid >> 7;                   // tap group
    const int t0  = gh << 2;                    // 0 or 4
    const int lane  = tid & 63;
    const int wv    = tid >> 6;
    const int nbase = wv << 5;
    const int m     = lane & 31;
    const int kh    = lane >> 5;

    const unsigned short* xtb = xt + (size_t)b * PLANE * 64;
    f32x16 acc = {};

    for (int cc = 0; cc < 4; ++cc) {
        __syncthreads();                        // prev MFMA done with ls
        const int cho = cc * 16;
        bf16x8 af[9];
        #pragma unroll
        for (int ks = 0; ks < 9; ++ks)
            af[ks] = *(const bf16x8*)&wobf[m * KTOT + cc * 144 + ks * 16 + kh * 8];
        #pragma unroll
        for (int i = 0; i < 5; ++i) {
            const int t = t0 + i;
            const int y  = ho - 1 + t / 3;
            const int xx = p  - 1 + t % 3;
            const bool ok = ((unsigned)y < (unsigned)H_) && ((unsigned)xx < (unsigned)W_);
            bf16x8 v0 = {}, v1 = {};
            if (ok) {
                const unsigned short* rp = xtb + ((y * W_ + xx) * 64 + cho);
                v0 = *(const bf16x8*)rp;
                v1 = *(const bf16x8*)(rp + 8);
            }
            *(bf16x8*)&ls[p * LSTRIDE + t * 16]     = v0;
            *(bf16x8*)&ls[p * LSTRIDE + t * 16 + 8] = v1;
        }
        __syncthreads();                        // ls ready
        #pragma unroll
        for (int ks = 0; ks < 9; ++ks) {
            bf16x8 s = *(const bf16x8*)&ls[(nbase + m) * LSTRIDE + ks * 16 + kh * 8];
            acc = __builtin_amdgcn_mfma_f32_32x32x16_bf16(af[ks], s, acc, 0, 0, 0);
        }
    }
    float* op = off_out + (size_t)b * MOFF * PLANE + ho * WO_ + (nbase + m);
    #pragma unroll
    for (int r = 0; r < 16; ++r) {
        int mo = (r & 3) + ((r >> 2) << 3) + (kh << 2);
        if (mo < MOFF) op[(size_t)mo * PLANE] = acc[r] + b_off[mo];
    }
}

// ---------------------------------------------------------------------------
// Deformable conv via MFMA. Block = (b,ho): M=64 out-ch x N=128 pixels.
// NHWC bf16 input: one bilinear corner = 32 contiguous bytes (16 channels);
// fp32 blend of 4 corners, f2bf to tap-major ls. MFMA/epilogue = R5-verified.
// ---------------------------------------------------------------------------
__global__ __launch_bounds__(256, 4) void dconv_mfma_kernel(const unsigned short* __restrict__ xt,
        const float* __restrict__ off, const unsigned short* __restrict__ wbf,
        const float* __restrict__ bias, float* __restrict__ out) {
    __shared__ __align__(16) unsigned short ls[128 * LSTRIDE];  // 38,912 B
    const int tid = threadIdx.x;
    const int id  = blockIdx.x;                 // 1024
    const int ho  = (id & 7) * 16 + ((id >> 3) & 15);   // XCD band swizzle
    const int b   = id >> 7;
    const int p   = tid & 127;                  // pixel = wo
    const int gh  = tid >> 7;                   // tap-group: 0 -> 0..4, 1 -> 4..8
    const int lane = tid & 63;
    const int wv   = tid >> 6;
    const int mbase = (wv & 1) << 5;
    const int nb0   = (wv >> 1) << 6;           // 0 or 64
    const int m  = lane & 31;
    const int kh = lane >> 5;
    const int t0 = gh << 2;                     // 0 or 4

    // ---- per-(pixel, tap-subset) bilinear setup (channel-independent) ----
    int   addr[5][4];                           // pixel index (y*W+x), clamped
    float cwt[5][4];                            // masked corner weights
    const float* offp = off + (size_t)b * MOFF * PLANE + ho * WO_ + p;
    #pragma unroll
    for (int i = 0; i < 5; ++i) {
        int t = t0 + i;
        float dy = offp[(2 * t) * PLANE];
        float dx = offp[(2 * t + 1) * PLANE];
        float py = (float)(ho - 1 + t / 3) + dy;
        float px = (float)(p  - 1 + t % 3) + dx;
        float fy = floorf(py), fx = floorf(px);
        float wy = py - fy,    wx = px - fx;
        int y0 = (int)fy, x0 = (int)fx;
        float wgt[4] = { (1.f - wy) * (1.f - wx), (1.f - wy) * wx,
                         wy * (1.f - wx),         wy * wx };
        #pragma unroll
        for (int c2 = 0; c2 < 4; ++c2) {
            int yy = y0 + (c2 >> 1);
            int xx = x0 + (c2 & 1);
            bool valid = ((unsigned)yy < (unsigned)H_) && ((unsigned)xx < (unsigned)W_);
            int yc = min(max(yy, 0), H_ - 1);
            int xc = min(max(xx, 0), W_ - 1);
            addr[i][c2] = yc * W_ + xc;
            cwt[i][c2]  = valid ? wgt[c2] : 0.f;
        }
    }

    const unsigned short* xtb = xt + (size_t)b * PLANE * 64;
    f32x16 acc[2] = {};
    for (int cc = 0; cc < 4; ++cc) {
        __syncthreads();                        // prev MFMA done with ls
        const int cho = cc * 16;
        bf16x8 af[9];
        #pragma unroll
        for (int ks = 0; ks < 9; ++ks)
            af[ks] = *(const bf16x8*)&wbf[(mbase + m) * KTOT + cc * 144 + ks * 16 + kh * 8];
        // sampling: 5 taps; per tap 4 corners x 32 contiguous bytes
        #pragma unroll
        for (int i = 0; i < 5; ++i) {
            float s[16];
            #pragma unroll
            for (int j = 0; j < 16; ++j) s[j] = 0.f;
            #pragma unroll
            for (int c2 = 0; c2 < 4; ++c2) {
                const unsigned short* rp = xtb + (addr[i][c2] * 64 + cho);
                bf16x8 u0 = *(const bf16x8*)rp;
                bf16x8 u1 = *(const bf16x8*)(rp + 8);
                float wgt = cwt[i][c2];
                #pragma unroll
                for (int j = 0; j < 8; ++j) {
                    s[j]     += wgt * bf2f(u0[j]);
                    s[8 + j] += wgt * bf2f(u1[j]);
                }
            }
            bf16x8 v0, v1;
            #pragma unroll
            for (int j = 0; j < 8; ++j) {
                v0[j] = (short)f2bf(s[j]);
                v1[j] = (short)f2bf(s[8 + j]);
            }
            int t = t0 + i;
            *(bf16x8*)&ls[p * LSTRIDE + t * 16]     = v0;
            *(bf16x8*)&ls[p * LSTRIDE + t * 16 + 8] = v1;
        }
        __syncthreads();                        // ls ready
        #pragma unroll
        for (int ks = 0; ks < 9; ++ks) {
            bf16x8 s0 = *(const bf16x8*)&ls[(nb0 + m) * LSTRIDE + ks * 16 + kh * 8];
            bf16x8 s1 = *(const bf16x8*)&ls[(nb0 + 32 + m) * LSTRIDE + ks * 16 + kh * 8];
            acc[0] = __builtin_amdgcn_mfma_f32_32x32x16_bf16(af[ks], s0, acc[0], 0, 0, 0);
            acc[1] = __builtin_amdgcn_mfma_f32_32x32x16_bf16(af[ks], s1, acc[1], 0, 0, 0);
        }
    }

    // epilogue: D col = pixel, row = out channel (32x32 C/D layout)
    #pragma unroll
    for (int nt = 0; nt < 2; ++nt) {
        int col = nb0 + nt * 32 + m;
        float* op = out + (size_t)b * O_ * PLANE + ho * WO_ + col;
        #pragma unroll
        for (int r = 0; r < 16; ++r) {
            int mo = mbase + (r & 3) + ((r >> 2) << 3) + (kh << 2);
            op[(size_t)mo * PLANE] = acc[nt][r] + bias[mo];
        }
    }
}

// ---------------------------------------------------------------------------
extern "C" void kernel_launch(void* const* d_in, const int* in_sizes, int n_in,
                              void* d_out, int out_size, void* d_ws, size_t ws_size,
                              hipStream_t stream) {
    const float* x     = (const float*)d_in[0];
    const float* w_off = (const float*)d_in[1];
    const float* b_off = (const float*)d_in[2];
    const float* w     = (const float*)d_in[3];
    const float* bias  = (const float*)d_in[4];
    float* out = (float*)d_out;

    float* off_ws = (float*)d_ws;                                   // 9.44 MB
    unsigned short* wbf  = (unsigned short*)(off_ws + (size_t)B_ * MOFF * PLANE); // 72 KB
    unsigned short* wobf = wbf + O_ * KTOT;                         // 36 KB
    unsigned short* xt   = wobf + 32 * KTOT;                        // 16.78 MB NHWC bf16

    cvt_w_kernel   <<<(O_ * KTOT + 255) / 256, 256, 0, stream>>>(w, wbf);
    cvt_woff_kernel<<<(32 * KTOT + 255) / 256, 256, 0, stream>>>(w_off, wobf);
    nhwc_kernel    <<<B_ * H_, 256, 0, stream>>>(x, xt);
    off_mfma_kernel  <<<B_ * HO_, 256, 0, stream>>>(xt, wobf, b_off, off_ws);
    dconv_mfma_kernel<<<B_ * HO_, 256, 0, stream>>>(xt, off_ws, wbf, bias, out);
}

// Round 7
// 228.807 us; speedup vs baseline: 2.9203x; 1.2685x over previous
//
#include <hip/hip_runtime.h>

// Problem constants (fixed by setup_inputs)
#define B_   8
#define C_   64
#define O_   64
#define H_   128
#define W_   128
#define HO_  128
#define WO_  128
#define K2_  9
#define MOFF 18          // 2*K*K offset channels
#define PLANE (H_*W_)    // 16384
#define KTOT 576         // C_*K2_
// LDS row stride in bf16 units: 304 B = 19 x 16B groups. Group stride 19 mod 32
// (odd) -> b128 ops across consecutive rows are conflict-free.
#define LSTRIDE 152

typedef short bf16x8 __attribute__((ext_vector_type(8)));
typedef float f32x16 __attribute__((ext_vector_type(16)));

__device__ __forceinline__ unsigned short f2bf(float f) {
    // round-to-nearest-even fp32 -> bf16
    unsigned u = __float_as_uint(f);
    u += 0x7fff + ((u >> 16) & 1);
    return (unsigned short)(u >> 16);
}
__device__ __forceinline__ float bf2f(short v) {
    return __uint_as_float(((unsigned)(unsigned short)v) << 16);
}

// ---------------------------------------------------------------------------
// cvt_w: main-conv weights -> bf16 rows [o][576] in TAP-MAJOR chunk order:
//   pos = cc*144 + t*16 + cl   <->   w[o][c = cc*16+cl][tap t]
// ---------------------------------------------------------------------------
__global__ __launch_bounds__(256) void cvt_w_kernel(const float* __restrict__ w,
                                                    unsigned short* __restrict__ wbf) {
    int i = blockIdx.x * 256 + threadIdx.x;     // 64*576 = 36864
    if (i >= O_ * KTOT) return;
    int o = i / KTOT, pos = i % KTOT;
    int cc = pos / 144, r = pos % 144, t = r / 16, cl = r % 16;
    wbf[i] = f2bf(w[o * KTOT + (cc * 16 + cl) * 9 + t]);
}

// cvt_woff: offset-conv weights, same TAP-MAJOR order, 32 rows (o>=18 zero).
__global__ __launch_bounds__(256) void cvt_woff_kernel(const float* __restrict__ w_off,
                                                       unsigned short* __restrict__ wobf) {
    int i = blockIdx.x * 256 + threadIdx.x;     // 32*576 = 18432
    if (i >= 32 * KTOT) return;
    int o = i / KTOT, pos = i % KTOT;
    int cc = pos / 144, r = pos % 144, t = r / 16, cl = r % 16;
    wobf[i] = (o < MOFF) ? f2bf(w_off[o * KTOT + (cc * 16 + cl) * 9 + t])
                         : (unsigned short)0;
}

// ---------------------------------------------------------------------------
// Chunk-major NHWC bf16 transpose:
//   xt[((cc*B + b)*PLANE + y*W + px)*16 + cl] = bf16(x[((b*64 + cc*16+cl)*H+y)*W+px])
// One 32-B granule holds 16 channels of one chunk for one pixel; adjacent
// pixels are adjacent in memory -> full 64-B line utilization for gathers.
// ---------------------------------------------------------------------------
__global__ __launch_bounds__(256) void nhwc_kernel(const float* __restrict__ x,
                                                   unsigned short* __restrict__ xt) {
    __shared__ unsigned short T[64 * 130];      // stride 130 (odd 16B groups)
    const int tid = threadIdx.x;
    const int y = blockIdx.x & 127;
    const int b = blockIdx.x >> 7;
    const float* src = x + (size_t)b * C_ * PLANE + y * W_;
    for (int i = tid; i < 64 * 128; i += 256) {
        int c = i >> 7, px = i & 127;
        T[c * 130 + px] = f2bf(src[c * PLANE + px]);
    }
    __syncthreads();
    for (int j = tid; j < 128 * 4; j += 256) {
        int px = j >> 2, cc = j & 3;
        unsigned short* dst = xt + ((size_t)(cc * B_ + b) * PLANE + y * W_ + px) * 16;
        ushort4 v0 = { T[(cc*16+ 0)*130+px], T[(cc*16+ 1)*130+px],
                       T[(cc*16+ 2)*130+px], T[(cc*16+ 3)*130+px] };
        ushort4 v1 = { T[(cc*16+ 4)*130+px], T[(cc*16+ 5)*130+px],
                       T[(cc*16+ 6)*130+px], T[(cc*16+ 7)*130+px] };
        ushort4 v2 = { T[(cc*16+ 8)*130+px], T[(cc*16+ 9)*130+px],
                       T[(cc*16+10)*130+px], T[(cc*16+11)*130+px] };
        ushort4 v3 = { T[(cc*16+12)*130+px], T[(cc*16+13)*130+px],
                       T[(cc*16+14)*130+px], T[(cc*16+15)*130+px] };
        *(ushort4*)(dst)      = v0;
        *(ushort4*)(dst + 4)  = v1;
        *(ushort4*)(dst + 8)  = v2;
        *(ushort4*)(dst + 12) = v3;
    }
}

// ---------------------------------------------------------------------------
// Offset conv via MFMA. Block = (b,ho): M=32 (18 used) x N=128 pixels.
// Chunk-major input: one tap = one 32-B contiguous read (two b128).
// Weights global->VGPR per chunk. Tap-major ls (pos = t*16+cl).
// ---------------------------------------------------------------------------
__global__ __launch_bounds__(256, 4) void off_mfma_kernel(const unsigned short* __restrict__ xt,
        const unsigned short* __restrict__ wobf, const float* __restrict__ b_off,
        float* __restrict__ off_out) {
    __shared__ __align__(16) unsigned short ls[128 * LSTRIDE];  // 38,912 B
    const int tid = threadIdx.x;
    const int id  = blockIdx.x;                 // 1024
    const int ho  = (id & 7) * 16 + ((id >> 3) & 15);   // XCD band swizzle
    const int b   = id >> 7;
    const int p   = tid & 127;                  // pixel = wo
    const int gh  = tid >> 7;                   // tap group
    const int t0  = gh << 2;                    // 0 or 4
    const int lane  = tid & 63;
    const int wv    = tid >> 6;
    const int nbase = wv << 5;
    const int m     = lane & 31;
    const int kh    = lane >> 5;

    f32x16 acc = {};

    for (int cc = 0; cc < 4; ++cc) {
        __syncthreads();                        // prev MFMA done with ls
        const unsigned short* xtc = xt + (size_t)(cc * B_ + b) * PLANE * 16;
        bf16x8 af[9];
        #pragma unroll
        for (int ks = 0; ks < 9; ++ks)
            af[ks] = *(const bf16x8*)&wobf[m * KTOT + cc * 144 + ks * 16 + kh * 8];
        #pragma unroll
        for (int i = 0; i < 5; ++i) {
            const int t = t0 + i;
            const int y  = ho - 1 + t / 3;
            const int xx = p  - 1 + t % 3;
            const bool ok = ((unsigned)y < (unsigned)H_) && ((unsigned)xx < (unsigned)W_);
            bf16x8 v0 = {}, v1 = {};
            if (ok) {
                const unsigned short* rp = xtc + (y * W_ + xx) * 16;
                v0 = *(const bf16x8*)rp;
                v1 = *(const bf16x8*)(rp + 8);
            }
            *(bf16x8*)&ls[p * LSTRIDE + t * 16]     = v0;
            *(bf16x8*)&ls[p * LSTRIDE + t * 16 + 8] = v1;
        }
        __syncthreads();                        // ls ready
        #pragma unroll
        for (int ks = 0; ks < 9; ++ks) {
            bf16x8 s = *(const bf16x8*)&ls[(nbase + m) * LSTRIDE + ks * 16 + kh * 8];
            acc = __builtin_amdgcn_mfma_f32_32x32x16_bf16(af[ks], s, acc, 0, 0, 0);
        }
    }
    float* op = off_out + (size_t)b * MOFF * PLANE + ho * WO_ + (nbase + m);
    #pragma unroll
    for (int r = 0; r < 16; ++r) {
        int mo = (r & 3) + ((r >> 2) << 3) + (kh << 2);
        if (mo < MOFF) op[(size_t)mo * PLANE] = acc[r] + b_off[mo];
    }
}

// ---------------------------------------------------------------------------
// Deformable conv via MFMA. Block = (b,ho): M=64 out-ch x N=128 pixels.
// Chunk-major input: one bilinear corner = one 32-B contiguous read;
// fp32 blend of 4 corners, f2bf to tap-major ls. MFMA/epilogue = verified.
// ---------------------------------------------------------------------------
__global__ __launch_bounds__(256, 4) void dconv_mfma_kernel(const unsigned short* __restrict__ xt,
        const float* __restrict__ off, const unsigned short* __restrict__ wbf,
        const float* __restrict__ bias, float* __restrict__ out) {
    __shared__ __align__(16) unsigned short ls[128 * LSTRIDE];  // 38,912 B
    const int tid = threadIdx.x;
    const int id  = blockIdx.x;                 // 1024
    const int ho  = (id & 7) * 16 + ((id >> 3) & 15);   // XCD band swizzle
    const int b   = id >> 7;
    const int p   = tid & 127;                  // pixel = wo
    const int gh  = tid >> 7;                   // tap-group: 0 -> 0..4, 1 -> 4..8
    const int lane = tid & 63;
    const int wv   = tid >> 6;
    const int mbase = (wv & 1) << 5;
    const int nb0   = (wv >> 1) << 6;           // 0 or 64
    const int m  = lane & 31;
    const int kh = lane >> 5;
    const int t0 = gh << 2;                     // 0 or 4

    // ---- per-(pixel, tap-subset) bilinear setup (channel-independent) ----
    int   addr[5][4];                           // pixel index (y*W+x), clamped
    float cwt[5][4];                            // masked corner weights
    const float* offp = off + (size_t)b * MOFF * PLANE + ho * WO_ + p;
    #pragma unroll
    for (int i = 0; i < 5; ++i) {
        int t = t0 + i;
        float dy = offp[(2 * t) * PLANE];
        float dx = offp[(2 * t + 1) * PLANE];
        float py = (float)(ho - 1 + t / 3) + dy;
        float px = (float)(p  - 1 + t % 3) + dx;
        float fy = floorf(py), fx = floorf(px);
        float wy = py - fy,    wx = px - fx;
        int y0 = (int)fy, x0 = (int)fx;
        float wgt[4] = { (1.f - wy) * (1.f - wx), (1.f - wy) * wx,
                         wy * (1.f - wx),         wy * wx };
        #pragma unroll
        for (int c2 = 0; c2 < 4; ++c2) {
            int yy = y0 + (c2 >> 1);
            int xx = x0 + (c2 & 1);
            bool valid = ((unsigned)yy < (unsigned)H_) && ((unsigned)xx < (unsigned)W_);
            int yc = min(max(yy, 0), H_ - 1);
            int xc = min(max(xx, 0), W_ - 1);
            addr[i][c2] = yc * W_ + xc;
            cwt[i][c2]  = valid ? wgt[c2] : 0.f;
        }
    }

    f32x16 acc[2] = {};
    for (int cc = 0; cc < 4; ++cc) {
        __syncthreads();                        // prev MFMA done with ls
        const unsigned short* xtc = xt + (size_t)(cc * B_ + b) * PLANE * 16;
        bf16x8 af[9];
        #pragma unroll
        for (int ks = 0; ks < 9; ++ks)
            af[ks] = *(const bf16x8*)&wbf[(mbase + m) * KTOT + cc * 144 + ks * 16 + kh * 8];
        // sampling: 5 taps; per tap 4 corners x 32 contiguous bytes
        #pragma unroll
        for (int i = 0; i < 5; ++i) {
            float s[16];
            #pragma unroll
            for (int j = 0; j < 16; ++j) s[j] = 0.f;
            #pragma unroll
            for (int c2 = 0; c2 < 4; ++c2) {
                const unsigned short* rp = xtc + addr[i][c2] * 16;
                bf16x8 u0 = *(const bf16x8*)rp;
                bf16x8 u1 = *(const bf16x8*)(rp + 8);
                float wgt = cwt[i][c2];
                #pragma unroll
                for (int j = 0; j < 8; ++j) {
                    s[j]     += wgt * bf2f(u0[j]);
                    s[8 + j] += wgt * bf2f(u1[j]);
                }
            }
            bf16x8 v0, v1;
            #pragma unroll
            for (int j = 0; j < 8; ++j) {
                v0[j] = (short)f2bf(s[j]);
                v1[j] = (short)f2bf(s[8 + j]);
            }
            int t = t0 + i;
            *(bf16x8*)&ls[p * LSTRIDE + t * 16]     = v0;
            *(bf16x8*)&ls[p * LSTRIDE + t * 16 + 8] = v1;
        }
        __syncthreads();                        // ls ready
        #pragma unroll
        for (int ks = 0; ks < 9; ++ks) {
            bf16x8 s0 = *(const bf16x8*)&ls[(nb0 + m) * LSTRIDE + ks * 16 + kh * 8];
            bf16x8 s1 = *(const bf16x8*)&ls[(nb0 + 32 + m) * LSTRIDE + ks * 16 + kh * 8];
            acc[0] = __builtin_amdgcn_mfma_f32_32x32x16_bf16(af[ks], s0, acc[0], 0, 0, 0);
            acc[1] = __builtin_amdgcn_mfma_f32_32x32x16_bf16(af[ks], s1, acc[1], 0, 0, 0);
        }
    }

    // epilogue: D col = pixel, row = out channel (32x32 C/D layout)
    #pragma unroll
    for (int nt = 0; nt < 2; ++nt) {
        int col = nb0 + nt * 32 + m;
        float* op = out + (size_t)b * O_ * PLANE + ho * WO_ + col;
        #pragma unroll
        for (int r = 0; r < 16; ++r) {
            int mo = mbase + (r & 3) + ((r >> 2) << 3) + (kh << 2);
            op[(size_t)mo * PLANE] = acc[nt][r] + bias[mo];
        }
    }
}

// ---------------------------------------------------------------------------
extern "C" void kernel_launch(void* const* d_in, const int* in_sizes, int n_in,
                              void* d_out, int out_size, void* d_ws, size_t ws_size,
                              hipStream_t stream) {
    const float* x     = (const float*)d_in[0];
    const float* w_off = (const float*)d_in[1];
    const float* b_off = (const float*)d_in[2];
    const float* w     = (const float*)d_in[3];
    const float* bias  = (const float*)d_in[4];
    float* out = (float*)d_out;

    float* off_ws = (float*)d_ws;                                   // 9.44 MB
    unsigned short* wbf  = (unsigned short*)(off_ws + (size_t)B_ * MOFF * PLANE); // 72 KB
    unsigned short* wobf = wbf + O_ * KTOT;                         // 36 KB
    unsigned short* xt   = wobf + 32 * KTOT;                        // 16.78 MB chunk-major

    cvt_w_kernel   <<<(O_ * KTOT + 255) / 256, 256, 0, stream>>>(w, wbf);
    cvt_woff_kernel<<<(32 * KTOT + 255) / 256, 256, 0, stream>>>(w_off, wobf);
    nhwc_kernel    <<<B_ * H_, 256, 0, stream>>>(x, xt);
    off_mfma_kernel  <<<B_ * HO_, 256, 0, stream>>>(xt, wobf, b_off, off_ws);
    dconv_mfma_kernel<<<B_ * HO_, 256, 0, stream>>>(xt, off_ws, wbf, bias, out);
}